// Round 4
// baseline (76.132 us; speedup 1.0000x reference)
//
#include <hip/hip_runtime.h>
#include <hip/hip_bf16.h>
#include <math.h>

#define NN    20000
#define NK    160000          // NN*8
#define NEDGE 320000
#define HID   256
#define INFEAT 128
#define EPSF  1e-5f

typedef __bf16  bf16x8 __attribute__((ext_vector_type(8)));
typedef float   f32x4  __attribute__((ext_vector_type(4)));
typedef ushort  u16x8  __attribute__((ext_vector_type(8)));

__device__ __forceinline__ float sigmoidf_(float x) { return 1.0f / (1.0f + expf(-x)); }

__device__ __forceinline__ ushort f2bf(float f) {
    __hip_bfloat16 h = __float2bfloat16(f);
    return __builtin_bit_cast(ushort, h);
}
__device__ __forceinline__ float bf2f(ushort u) {
    return __builtin_bit_cast(float, ((unsigned int)u) << 16);
}
__device__ __forceinline__ int wrapN(int v) {
    return (v < 0) ? v + NN : ((v >= NN) ? v - NN : v);
}

#define LDSP(p) ((__attribute__((address_space(3))) unsigned int*)(p))
#define GBLP(p) ((const __attribute__((address_space(1))) unsigned int*)(p))
#define GLD16(g, l) __builtin_amdgcn_global_load_lds(GBLP(g), LDSP(l), 16, 0, 0)

// ---------------- prep: W1^T, W2^T in bf16 ----------------
// blocks [0,32): W1t (32768 el). [32,96): W2t (65536 el).
__global__ __launch_bounds__(256) void prep_w(const float* __restrict__ W1,
                                              const float* __restrict__ W2,
                                              ushort* __restrict__ W1t,
                                              ushort* __restrict__ W2t)
{
    const int b = blockIdx.x, t = threadIdx.x;
    if (b < 32) {
        const int e = b * 1024 + t * 4;
        ushort4 o;
        #pragma unroll
        for (int j = 0; j < 4; ++j) {
            const int ee = e + j;
            const int n = ee >> 7, k = ee & 127;   // W1t[n][k] = W1[k][n]
            ((ushort*)&o)[j] = f2bf(W1[k * 256 + n]);
        }
        *reinterpret_cast<ushort4*>(W1t + e) = o;
    } else {
        const int e = (b - 32) * 1024 + t * 4;
        ushort4 o;
        #pragma unroll
        for (int j = 0; j < 4; ++j) {
            const int ee = e + j;
            const int n = ee >> 8, k = ee & 255;   // W2t[n][k] = W2[k][n]
            ((ushort*)&o)[j] = f2bf(W2[k * 256 + n]);
        }
        *reinterpret_cast<ushort4*>(W2t + e) = o;
    }
}

// ---------------- GEMM1: H1[M,256] = cast_bf16(x[M,128]) @ W1 (W1t[256][128]) ----
// 64x256 tile, grid 313. 4 waves, wave -> 32x32 quadrant, cn loop over col groups.
// LDS rows 128B, XOR swizzle: phys_chunk = log_chunk ^ (row&7).
__global__ __launch_bounds__(256) void gemm1_kernel(const float* __restrict__ X,
                                                    const ushort* __restrict__ Bt,
                                                    ushort* __restrict__ C)
{
    __shared__ alignas(16) char As[8192];     // 64 x 128B
    __shared__ alignas(16) char Bs[32768];    // 256 x 128B

    const int bm = blockIdx.x * 64;
    const int t = threadIdx.x;
    const int wave = t >> 6, lane = t & 63;
    const int wr = (wave >> 1) * 32;
    const int wc = (wave & 1) * 32;

    f32x4 acc[4][2][2] = {};

    #pragma unroll
    for (int kt = 0; kt < 2; ++kt) {
        const int k0 = kt * 64;
        // --- stage A (reg path: f32 -> bf16), 2 chunks of 16B per thread ---
        #pragma unroll
        for (int j = 0; j < 2; ++j) {
            const int c   = t * 2 + j;
            const int row = c >> 3;
            const int lk  = c & 7;
            const int pc  = lk ^ (row & 7);
            int rg = bm + row; if (rg >= NN) rg = NN - 1;
            const float4 v0 = *reinterpret_cast<const float4*>(X + (size_t)rg * INFEAT + k0 + lk * 8);
            const float4 v1 = *reinterpret_cast<const float4*>(X + (size_t)rg * INFEAT + k0 + lk * 8 + 4);
            u16x8 p;
            p[0] = f2bf(v0.x); p[1] = f2bf(v0.y); p[2] = f2bf(v0.z); p[3] = f2bf(v0.w);
            p[4] = f2bf(v1.x); p[5] = f2bf(v1.y); p[6] = f2bf(v1.z); p[7] = f2bf(v1.w);
            *reinterpret_cast<u16x8*>(As + row * 128 + pc * 16) = p;
        }
        // --- stage B (all 256 cols x 64 k): 8 GLD16 per wave ---
        #pragma unroll
        for (int it = 0; it < 8; ++it) {
            const int cb  = (it * 4 + wave) * 64 + lane;
            const int row = cb >> 3;
            const int lk  = (cb & 7) ^ (row & 7);
            GLD16(Bt + (size_t)row * INFEAT + k0 + lk * 8, Bs + (it * 4 + wave) * 1024);
        }
        __syncthreads();

        // A fragments (shared across cn)
        bf16x8 af[2][2];
        #pragma unroll
        for (int kk = 0; kk < 2; ++kk) {
            const int klog = kk * 64 + ((lane >> 4) << 4);
            #pragma unroll
            for (int mi = 0; mi < 2; ++mi) {
                const int row = wr + mi * 16 + (lane & 15);
                af[kk][mi] = *reinterpret_cast<const bf16x8*>(As + row * 128 + (klog ^ ((row & 7) << 4)));
            }
        }
        #pragma unroll
        for (int cn = 0; cn < 4; ++cn) {
            #pragma unroll
            for (int kk = 0; kk < 2; ++kk) {
                const int klog = kk * 64 + ((lane >> 4) << 4);
                bf16x8 bfv[2];
                #pragma unroll
                for (int ni = 0; ni < 2; ++ni) {
                    const int row = cn * 64 + wc + ni * 16 + (lane & 15);
                    bfv[ni] = *reinterpret_cast<const bf16x8*>(Bs + row * 128 + (klog ^ ((row & 7) << 4)));
                }
                #pragma unroll
                for (int mi = 0; mi < 2; ++mi)
                    #pragma unroll
                    for (int ni = 0; ni < 2; ++ni)
                        acc[cn][mi][ni] = __builtin_amdgcn_mfma_f32_16x16x32_bf16(af[kk][mi], bfv[ni], acc[cn][mi][ni], 0, 0, 0);
            }
        }
        __syncthreads();
    }

    #pragma unroll
    for (int cn = 0; cn < 4; ++cn)
        #pragma unroll
        for (int mi = 0; mi < 2; ++mi)
            #pragma unroll
            for (int ni = 0; ni < 2; ++ni)
                #pragma unroll
                for (int r = 0; r < 4; ++r) {
                    const int row = bm + wr + mi * 16 + ((lane >> 4) << 2) + r;
                    if (row < NN)
                        C[(size_t)row * 256 + cn * 64 + wc + ni * 16 + (lane & 15)] = f2bf(acc[cn][mi][ni][r]);
                }
}

// ---------------- GEMM2: H2 = relu(bn(A)) @ W2 (W2t[256][256]), BN fused in staging ----
__global__ __launch_bounds__(256) void gemm2_kernel(const ushort* __restrict__ Ab,
                                                    const float* __restrict__ ss,
                                                    const ushort* __restrict__ Bt,
                                                    ushort* __restrict__ C)
{
    __shared__ alignas(16) char As[8192];
    __shared__ alignas(16) char Bs[32768];

    const int bm = blockIdx.x * 64;
    const int t = threadIdx.x;
    const int wave = t >> 6, lane = t & 63;
    const int wr = (wave >> 1) * 32;
    const int wc = (wave & 1) * 32;

    f32x4 acc[4][2][2] = {};

    #pragma unroll
    for (int kt = 0; kt < 4; ++kt) {
        const int k0 = kt * 64;
        // --- stage A with BN+relu (bf16 in, bf16 out) ---
        #pragma unroll
        for (int j = 0; j < 2; ++j) {
            const int c   = t * 2 + j;
            const int row = c >> 3;
            const int lk  = c & 7;
            const int pc  = lk ^ (row & 7);
            int rg = bm + row; if (rg >= NN) rg = NN - 1;
            const int f0 = k0 + lk * 8;
            const u16x8 a = *reinterpret_cast<const u16x8*>(Ab + (size_t)rg * 256 + f0);
            const float4 sc0 = *reinterpret_cast<const float4*>(ss + f0);
            const float4 sc1 = *reinterpret_cast<const float4*>(ss + f0 + 4);
            const float4 sh0 = *reinterpret_cast<const float4*>(ss + 256 + f0);
            const float4 sh1 = *reinterpret_cast<const float4*>(ss + 256 + f0 + 4);
            u16x8 p;
            p[0] = f2bf(fmaxf(bf2f(a[0]) * sc0.x + sh0.x, 0.f));
            p[1] = f2bf(fmaxf(bf2f(a[1]) * sc0.y + sh0.y, 0.f));
            p[2] = f2bf(fmaxf(bf2f(a[2]) * sc0.z + sh0.z, 0.f));
            p[3] = f2bf(fmaxf(bf2f(a[3]) * sc0.w + sh0.w, 0.f));
            p[4] = f2bf(fmaxf(bf2f(a[4]) * sc1.x + sh1.x, 0.f));
            p[5] = f2bf(fmaxf(bf2f(a[5]) * sc1.y + sh1.y, 0.f));
            p[6] = f2bf(fmaxf(bf2f(a[6]) * sc1.z + sh1.z, 0.f));
            p[7] = f2bf(fmaxf(bf2f(a[7]) * sc1.w + sh1.w, 0.f));
            *reinterpret_cast<u16x8*>(As + row * 128 + pc * 16) = p;
        }
        // --- stage B ---
        #pragma unroll
        for (int it = 0; it < 8; ++it) {
            const int cb  = (it * 4 + wave) * 64 + lane;
            const int row = cb >> 3;
            const int lk  = (cb & 7) ^ (row & 7);
            GLD16(Bt + (size_t)row * 256 + k0 + lk * 8, Bs + (it * 4 + wave) * 1024);
        }
        __syncthreads();

        bf16x8 af[2][2];
        #pragma unroll
        for (int kk = 0; kk < 2; ++kk) {
            const int klog = kk * 64 + ((lane >> 4) << 4);
            #pragma unroll
            for (int mi = 0; mi < 2; ++mi) {
                const int row = wr + mi * 16 + (lane & 15);
                af[kk][mi] = *reinterpret_cast<const bf16x8*>(As + row * 128 + (klog ^ ((row & 7) << 4)));
            }
        }
        #pragma unroll
        for (int cn = 0; cn < 4; ++cn) {
            #pragma unroll
            for (int kk = 0; kk < 2; ++kk) {
                const int klog = kk * 64 + ((lane >> 4) << 4);
                bf16x8 bfv[2];
                #pragma unroll
                for (int ni = 0; ni < 2; ++ni) {
                    const int row = cn * 64 + wc + ni * 16 + (lane & 15);
                    bfv[ni] = *reinterpret_cast<const bf16x8*>(Bs + row * 128 + (klog ^ ((row & 7) << 4)));
                }
                #pragma unroll
                for (int mi = 0; mi < 2; ++mi)
                    #pragma unroll
                    for (int ni = 0; ni < 2; ++ni)
                        acc[cn][mi][ni] = __builtin_amdgcn_mfma_f32_16x16x32_bf16(af[kk][mi], bfv[ni], acc[cn][mi][ni], 0, 0, 0);
            }
        }
        __syncthreads();
    }

    #pragma unroll
    for (int cn = 0; cn < 4; ++cn)
        #pragma unroll
        for (int mi = 0; mi < 2; ++mi)
            #pragma unroll
            for (int ni = 0; ni < 2; ++ni)
                #pragma unroll
                for (int r = 0; r < 4; ++r) {
                    const int row = bm + wr + mi * 16 + ((lane >> 4) << 2) + r;
                    if (row < NN)
                        C[(size_t)row * 256 + cn * 64 + wc + ni * 16 + (lane & 15)] = f2bf(acc[cn][mi][ni][r]);
                }
}

// ---------------- agg1 (rolling 17-tap) + bias, fused BN partial stats ----------
__global__ __launch_bounds__(256) void agg1_bn(const ushort* __restrict__ H1,
                                               const float* __restrict__ b1,
                                               ushort* __restrict__ A,
                                               float* __restrict__ part)
{
    const int b = blockIdx.x, f = threadIdx.x;
    const int v0 = b * 32;
    const float bias = b1[f];
    float S = 0.f;
    #pragma unroll
    for (int o = -8; o <= 8; ++o)
        S += bf2f(H1[(size_t)wrapN(v0 + o) * 256 + f]);
    float s = 0.f, s2 = 0.f;
    const float inv17 = 1.0f / 17.0f;
    for (int i = 0; i < 32; ++i) {
        const int v = v0 + i;
        const float add = bf2f(H1[(size_t)wrapN(v + 9) * 256 + f]);
        const float sub = bf2f(H1[(size_t)wrapN(v - 8) * 256 + f]);
        const float val = S * inv17 + bias;
        A[(size_t)v * 256 + f] = f2bf(val);
        s += val; s2 += val * val;
        S += add - sub;
    }
    part[(size_t)b * 512 + f]       = s;
    part[(size_t)b * 512 + 256 + f] = s2;
}

// ---------------- BN reduce tree ----------------
__global__ __launch_bounds__(512) void bn_reduce(const float* __restrict__ part,
                                                 float* __restrict__ part2)
{
    const int b = blockIdx.x, t = threadIdx.x;
    float s = 0.f;
    #pragma unroll 5
    for (int r = b * 25; r < b * 25 + 25; ++r)
        s += part[(size_t)r * 512 + t];
    part2[(size_t)b * 512 + t] = s;
}

__global__ __launch_bounds__(512) void bn_finalize(const float* __restrict__ part2,
                                                   const float* __restrict__ gamma,
                                                   const float* __restrict__ beta,
                                                   float* __restrict__ ss)
{
    const int t = threadIdx.x;
    __shared__ float red[512];
    float s = 0.f;
    #pragma unroll 5
    for (int b = 0; b < 25; ++b)
        s += part2[(size_t)b * 512 + t];
    red[t] = s;
    __syncthreads();
    if (t < 256) {
        const float invn = 1.0f / (float)NN;
        const float mu   = red[t] * invn;
        const float var  = red[t + 256] * invn - mu * mu;
        const float sc   = gamma[t] * rsqrtf(var + EPSF);
        ss[t]       = sc;
        ss[256 + t] = beta[t] - mu * sc;
    }
}

// ---------------- agg2 (rolling) + bias + relu + dot with Wl -> u, w ----------
__global__ __launch_bounds__(256) void agg2_dots(const ushort* __restrict__ H2,
                                                 const float* __restrict__ b2,
                                                 const float* __restrict__ Wl,
                                                 float* __restrict__ u,
                                                 float* __restrict__ w)
{
    const int b = blockIdx.x, t = threadIdx.x;
    const int wave = t >> 6, lane = t & 63;
    const int v0 = b * 32;
    const float wla = Wl[t], wlb = Wl[256 + t], bias = b2[t];
    __shared__ float Up[4][32], Wp[4][32];

    float S = 0.f;
    #pragma unroll
    for (int o = -8; o <= 8; ++o)
        S += bf2f(H2[(size_t)wrapN(v0 + o) * 256 + t]);

    const float inv17 = 1.0f / 17.0f;
    for (int i = 0; i < 32; ++i) {
        const int v = v0 + i;
        const float add = bf2f(H2[(size_t)wrapN(v + 9) * 256 + t]);
        const float sub = bf2f(H2[(size_t)wrapN(v - 8) * 256 + t]);
        const float h = fmaxf(S * inv17 + bias, 0.f);
        float pu = h * wla, pw = h * wlb;
        #pragma unroll
        for (int off = 32; off > 0; off >>= 1) {
            pu += __shfl_down(pu, off);
            pw += __shfl_down(pw, off);
        }
        if (lane == 0) { Up[wave][i] = pu; Wp[wave][i] = pw; }
        S += add - sub;
    }
    __syncthreads();
    if (t < 32) {
        u[v0 + t] = Up[0][t] + Up[1][t] + Up[2][t] + Up[3][t];
        w[v0 + t] = Wp[0][t] + Wp[1][t] + Wp[2][t] + Wp[3][t];
    }
}

// ---------------- P[v] = u[v] + 16*w[v] + sum_{o=1..8}(u[v+o]+u[v-o]) ----------
__global__ __launch_bounds__(256) void compP(const float* __restrict__ u,
                                             const float* __restrict__ w,
                                             float* __restrict__ P)
{
    const int v = blockIdx.x * 256 + threadIdx.x;
    if (v >= NN) return;
    float s = u[v] + 16.0f * w[v];
    #pragma unroll
    for (int o = 1; o <= 8; ++o) {
        int vp = v + o;  if (vp >= NN) vp -= NN;
        int vm = v - o;  if (vm < 0)   vm += NN;
        s += u[vp] + u[vm];
    }
    P[v] = s;
}

// ---------------- final per-edge output ----------------
__global__ __launch_bounds__(256) void out_kernel(const float* __restrict__ P,
                                                  const float* __restrict__ w,
                                                  const float* __restrict__ blp,
                                                  float* __restrict__ out)
{
    const int c = blockIdx.x * 256 + threadIdx.x;
    if (c >= NEDGE) return;
    int v, tt;
    if (c < NK) {
        v = c >> 3;
        tt = v + 1 + (c & 7);
        if (tt >= NN) tt -= NN;
    } else {
        const int e = c - NK;
        tt = e >> 3;
        v = tt + 1 + (e & 7);
        if (v >= NN) v -= NN;
    }
    const float val = (P[v] + w[tt]) * (1.0f / 17.0f) + blp[0];
    out[c] = sigmoidf_(val);
}

// ---------------- launch ----------------
extern "C" void kernel_launch(void* const* d_in, const int* in_sizes, int n_in,
                              void* d_out, int out_size, void* d_ws, size_t ws_size,
                              hipStream_t stream)
{
    const float* x      = (const float*)d_in[0];
    const float* W1     = (const float*)d_in[1];
    const float* b1     = (const float*)d_in[2];
    const float* gamma1 = (const float*)d_in[3];
    const float* beta1  = (const float*)d_in[4];
    const float* W2     = (const float*)d_in[5];
    const float* b2     = (const float*)d_in[6];
    const float* Wl     = (const float*)d_in[7];
    const float* bl     = (const float*)d_in[8];
    float* out = (float*)d_out;

    float* part  = (float*)d_ws;                     // [625,512]
    float* part2 = part + 625 * 512;                 // [25,512]
    float* ss    = part2 + 25 * 512;                 // [512]
    float* u     = ss + 512;                         // [NN]
    float* wv    = u + NN;                           // [NN]
    float* P     = wv + NN;                          // [NN]
    ushort* A    = (ushort*)(P + NN);                // [NN,256] bf16
    ushort* H    = A + (size_t)NN * 256;             // [NN,256] bf16 (H1/H2)
    ushort* W1t  = H + (size_t)NN * 256;             // [256,128]
    ushort* W2t  = W1t + 256 * 128;                  // [256,256]

    // 1) weight transposes
    prep_w<<<96, 256, 0, stream>>>(W1, W2, W1t, W2t);
    // 2) H1 = cast(x) @ W1
    gemm1_kernel<<<313, 256, 0, stream>>>(x, W1t, H);
    // 3) agg1 + b1 -> A (bf16), fused BN partials
    agg1_bn<<<625, 256, 0, stream>>>(H, b1, A, part);
    // 4) BN reduce + finalize
    bn_reduce<<<25, 512, 0, stream>>>(part, part2);
    bn_finalize<<<1, 512, 0, stream>>>(part2, gamma1, beta1, ss);
    // 5) H2 = relu(bn(A)) @ W2   (BN fused in staging)
    gemm2_kernel<<<313, 256, 0, stream>>>(A, ss, W2t, H);
    // 6) agg2 + b2 + relu + dots -> u, w
    agg2_dots<<<625, 256, 0, stream>>>(H, b2, Wl, u, wv);
    // 7) P
    compP<<<(NN + 255) / 256, 256, 0, stream>>>(u, wv, P);
    // 8) edge outputs
    out_kernel<<<(NEDGE + 255) / 256, 256, 0, stream>>>(P, wv, bl, out);
}

// Round 5
// 67.523 us; speedup vs baseline: 1.1275x; 1.1275x over previous
//
#include <hip/hip_runtime.h>
#include <hip/hip_bf16.h>
#include <math.h>

#define NN    20000
#define NK    160000          // NN*8
#define NEDGE 320000
#define HID   256
#define INFEAT 128
#define EPSF  1e-5f

typedef __bf16  bf16x8 __attribute__((ext_vector_type(8)));
typedef float   f32x4  __attribute__((ext_vector_type(4)));
typedef ushort  u16x8  __attribute__((ext_vector_type(8)));

__device__ __forceinline__ float sigmoidf_(float x) { return 1.0f / (1.0f + expf(-x)); }

__device__ __forceinline__ ushort f2bf(float f) {
    __hip_bfloat16 h = __float2bfloat16(f);
    return __builtin_bit_cast(ushort, h);
}
__device__ __forceinline__ float bf2f(ushort u) {
    return __builtin_bit_cast(float, ((unsigned int)u) << 16);
}
__device__ __forceinline__ int wrapN(int v) {
    return (v < 0) ? v + NN : ((v >= NN) ? v - NN : v);
}

#define LDSP(p) ((__attribute__((address_space(3))) unsigned int*)(p))
#define GBLP(p) ((const __attribute__((address_space(1))) unsigned int*)(p))
#define GLD16(g, l) __builtin_amdgcn_global_load_lds(GBLP(g), LDSP(l), 16, 0, 0)

// ---------------- prep: W1^T, W2^T in bf16 ----------------
__global__ __launch_bounds__(256) void prep_w(const float* __restrict__ W1,
                                              const float* __restrict__ W2,
                                              ushort* __restrict__ W1t,
                                              ushort* __restrict__ W2t)
{
    const int b = blockIdx.x, t = threadIdx.x;
    if (b < 32) {
        const int e = b * 1024 + t * 4;
        ushort4 o;
        #pragma unroll
        for (int j = 0; j < 4; ++j) {
            const int ee = e + j;
            const int n = ee >> 7, k = ee & 127;   // W1t[n][k] = W1[k][n]
            ((ushort*)&o)[j] = f2bf(W1[k * 256 + n]);
        }
        *reinterpret_cast<ushort4*>(W1t + e) = o;
    } else {
        const int e = (b - 32) * 1024 + t * 4;
        ushort4 o;
        #pragma unroll
        for (int j = 0; j < 4; ++j) {
            const int ee = e + j;
            const int n = ee >> 8, k = ee & 255;   // W2t[n][k] = W2[k][n]
            ((ushort*)&o)[j] = f2bf(W2[k * 256 + n]);
        }
        *reinterpret_cast<ushort4*>(W2t + e) = o;
    }
}

// ======== GEMM common geometry ========
// Tile 64 (M) x 128 (N), BK=64, 512 threads = 8 waves (2 row-quads x 4 col-quads).
// LDS rows are 128B (64 bf16), XOR swizzle on 16B chunks: phys = log ^ (row&7).

// ---------------- GEMM1: H1 = cast_bf16(x) @ W1 (W1t[256][128]) ----------------
__global__ __launch_bounds__(512) void gemm1_kernel(const float* __restrict__ X,
                                                    const ushort* __restrict__ Bt,
                                                    ushort* __restrict__ C)
{
    __shared__ alignas(16) char As[8192];     // 64 rows x 128B
    __shared__ alignas(16) char Bs[16384];    // 128 rows x 128B

    const int bm = blockIdx.x * 64;
    const int bn = blockIdx.y * 128;
    const int t = threadIdx.x;
    const int wave = t >> 6, lane = t & 63;
    const int wr = (wave >> 2) * 32;
    const int wc = (wave & 3) * 32;

    f32x4 acc[2][2] = {};

    for (int kt = 0; kt < 2; ++kt) {
        const int k0 = kt * 64;
        // --- stage A: f32 -> bf16, 1 chunk (16B) per thread ---
        {
            const int row = t >> 3;
            const int lk  = t & 7;
            const int pc  = lk ^ (row & 7);
            int rg = bm + row; if (rg >= NN) rg = NN - 1;
            const float4 v0 = *reinterpret_cast<const float4*>(X + (size_t)rg * INFEAT + k0 + lk * 8);
            const float4 v1 = *reinterpret_cast<const float4*>(X + (size_t)rg * INFEAT + k0 + lk * 8 + 4);
            u16x8 p;
            p[0] = f2bf(v0.x); p[1] = f2bf(v0.y); p[2] = f2bf(v0.z); p[3] = f2bf(v0.w);
            p[4] = f2bf(v1.x); p[5] = f2bf(v1.y); p[6] = f2bf(v1.z); p[7] = f2bf(v1.w);
            *reinterpret_cast<u16x8*>(As + row * 128 + pc * 16) = p;
        }
        // --- stage B: 128 rows x 64 k = 1024 chunks, 2 GLD16 rounds ---
        #pragma unroll
        for (int it = 0; it < 2; ++it) {
            const int cb  = (it * 8 + wave) * 64 + lane;
            const int row = cb >> 3;
            const int lk  = (cb & 7) ^ (row & 7);
            GLD16(Bt + (size_t)(bn + row) * INFEAT + k0 + lk * 8, Bs + (it * 8 + wave) * 1024);
        }
        __syncthreads();

        #pragma unroll
        for (int kk = 0; kk < 2; ++kk) {
            const int klog = kk * 64 + ((lane >> 4) << 4);
            bf16x8 af[2], bfv[2];
            #pragma unroll
            for (int mi = 0; mi < 2; ++mi) {
                const int row = wr + mi * 16 + (lane & 15);
                af[mi] = *reinterpret_cast<const bf16x8*>(As + row * 128 + (klog ^ ((row & 7) << 4)));
            }
            #pragma unroll
            for (int ni = 0; ni < 2; ++ni) {
                const int row = wc + ni * 16 + (lane & 15);
                bfv[ni] = *reinterpret_cast<const bf16x8*>(Bs + row * 128 + (klog ^ ((row & 7) << 4)));
            }
            #pragma unroll
            for (int mi = 0; mi < 2; ++mi)
                #pragma unroll
                for (int ni = 0; ni < 2; ++ni)
                    acc[mi][ni] = __builtin_amdgcn_mfma_f32_16x16x32_bf16(af[mi], bfv[ni], acc[mi][ni], 0, 0, 0);
        }
        __syncthreads();
    }

    #pragma unroll
    for (int mi = 0; mi < 2; ++mi)
        #pragma unroll
        for (int ni = 0; ni < 2; ++ni)
            #pragma unroll
            for (int r = 0; r < 4; ++r) {
                const int row = bm + wr + mi * 16 + ((lane >> 4) << 2) + r;
                if (row < NN)
                    C[(size_t)row * 256 + bn + wc + ni * 16 + (lane & 15)] = f2bf(acc[mi][ni][r]);
            }
}

// ---------------- GEMM2: H2 = relu(bn(A)) @ W2 (W2t[256][256]) ----------------
__global__ __launch_bounds__(512) void gemm2_kernel(const ushort* __restrict__ Ab,
                                                    const float* __restrict__ ss,
                                                    const ushort* __restrict__ Bt,
                                                    ushort* __restrict__ C)
{
    __shared__ alignas(16) char As[8192];
    __shared__ alignas(16) char Bs[16384];

    const int bm = blockIdx.x * 64;
    const int bn = blockIdx.y * 128;
    const int t = threadIdx.x;
    const int wave = t >> 6, lane = t & 63;
    const int wr = (wave >> 2) * 32;
    const int wc = (wave & 3) * 32;

    f32x4 acc[2][2] = {};

    for (int kt = 0; kt < 4; ++kt) {
        const int k0 = kt * 64;
        // --- stage A with BN + relu fused (bf16 in / bf16 out) ---
        {
            const int row = t >> 3;
            const int lk  = t & 7;
            const int pc  = lk ^ (row & 7);
            int rg = bm + row; if (rg >= NN) rg = NN - 1;
            const int f0 = k0 + lk * 8;
            const u16x8 a = *reinterpret_cast<const u16x8*>(Ab + (size_t)rg * 256 + f0);
            const float4 sc0 = *reinterpret_cast<const float4*>(ss + f0);
            const float4 sc1 = *reinterpret_cast<const float4*>(ss + f0 + 4);
            const float4 sh0 = *reinterpret_cast<const float4*>(ss + 256 + f0);
            const float4 sh1 = *reinterpret_cast<const float4*>(ss + 256 + f0 + 4);
            u16x8 p;
            p[0] = f2bf(fmaxf(bf2f(a[0]) * sc0.x + sh0.x, 0.f));
            p[1] = f2bf(fmaxf(bf2f(a[1]) * sc0.y + sh0.y, 0.f));
            p[2] = f2bf(fmaxf(bf2f(a[2]) * sc0.z + sh0.z, 0.f));
            p[3] = f2bf(fmaxf(bf2f(a[3]) * sc0.w + sh0.w, 0.f));
            p[4] = f2bf(fmaxf(bf2f(a[4]) * sc1.x + sh1.x, 0.f));
            p[5] = f2bf(fmaxf(bf2f(a[5]) * sc1.y + sh1.y, 0.f));
            p[6] = f2bf(fmaxf(bf2f(a[6]) * sc1.z + sh1.z, 0.f));
            p[7] = f2bf(fmaxf(bf2f(a[7]) * sc1.w + sh1.w, 0.f));
            *reinterpret_cast<u16x8*>(As + row * 128 + pc * 16) = p;
        }
        // --- stage B ---
        #pragma unroll
        for (int it = 0; it < 2; ++it) {
            const int cb  = (it * 8 + wave) * 64 + lane;
            const int row = cb >> 3;
            const int lk  = (cb & 7) ^ (row & 7);
            GLD16(Bt + (size_t)(bn + row) * 256 + k0 + lk * 8, Bs + (it * 8 + wave) * 1024);
        }
        __syncthreads();

        #pragma unroll
        for (int kk = 0; kk < 2; ++kk) {
            const int klog = kk * 64 + ((lane >> 4) << 4);
            bf16x8 af[2], bfv[2];
            #pragma unroll
            for (int mi = 0; mi < 2; ++mi) {
                const int row = wr + mi * 16 + (lane & 15);
                af[mi] = *reinterpret_cast<const bf16x8*>(As + row * 128 + (klog ^ ((row & 7) << 4)));
            }
            #pragma unroll
            for (int ni = 0; ni < 2; ++ni) {
                const int row = wc + ni * 16 + (lane & 15);
                bfv[ni] = *reinterpret_cast<const bf16x8*>(Bs + row * 128 + (klog ^ ((row & 7) << 4)));
            }
            #pragma unroll
            for (int mi = 0; mi < 2; ++mi)
                #pragma unroll
                for (int ni = 0; ni < 2; ++ni)
                    acc[mi][ni] = __builtin_amdgcn_mfma_f32_16x16x32_bf16(af[mi], bfv[ni], acc[mi][ni], 0, 0, 0);
        }
        __syncthreads();
    }

    #pragma unroll
    for (int mi = 0; mi < 2; ++mi)
        #pragma unroll
        for (int ni = 0; ni < 2; ++ni)
            #pragma unroll
            for (int r = 0; r < 4; ++r) {
                const int row = bm + wr + mi * 16 + ((lane >> 4) << 2) + r;
                if (row < NN)
                    C[(size_t)row * 256 + bn + wc + ni * 16 + (lane & 15)] = f2bf(acc[mi][ni][r]);
            }
}

// ---------------- agg1 (rolling 17-tap) + bias, fused BN partial stats ----------
__global__ __launch_bounds__(256) void agg1_bn(const ushort* __restrict__ H1,
                                               const float* __restrict__ b1,
                                               ushort* __restrict__ A,
                                               float* __restrict__ part)
{
    const int b = blockIdx.x, f = threadIdx.x;
    const int v0 = b * 32;
    const float bias = b1[f];
    float S = 0.f;
    #pragma unroll
    for (int o = -8; o <= 8; ++o)
        S += bf2f(H1[(size_t)wrapN(v0 + o) * 256 + f]);
    float s = 0.f, s2 = 0.f;
    const float inv17 = 1.0f / 17.0f;
    for (int i = 0; i < 32; ++i) {
        const int v = v0 + i;
        const float add = bf2f(H1[(size_t)wrapN(v + 9) * 256 + f]);
        const float sub = bf2f(H1[(size_t)wrapN(v - 8) * 256 + f]);
        const float val = S * inv17 + bias;
        A[(size_t)v * 256 + f] = f2bf(val);
        s += val; s2 += val * val;
        S += add - sub;
    }
    part[(size_t)b * 512 + f]       = s;
    part[(size_t)b * 512 + 256 + f] = s2;
}

// ---------------- BN reduce tree ----------------
__global__ __launch_bounds__(512) void bn_reduce(const float* __restrict__ part,
                                                 float* __restrict__ part2)
{
    const int b = blockIdx.x, t = threadIdx.x;
    float s = 0.f;
    #pragma unroll 5
    for (int r = b * 25; r < b * 25 + 25; ++r)
        s += part[(size_t)r * 512 + t];
    part2[(size_t)b * 512 + t] = s;
}

__global__ __launch_bounds__(512) void bn_finalize(const float* __restrict__ part2,
                                                   const float* __restrict__ gamma,
                                                   const float* __restrict__ beta,
                                                   float* __restrict__ ss)
{
    const int t = threadIdx.x;
    __shared__ float red[512];
    float s = 0.f;
    #pragma unroll 5
    for (int b = 0; b < 25; ++b)
        s += part2[(size_t)b * 512 + t];
    red[t] = s;
    __syncthreads();
    if (t < 256) {
        const float invn = 1.0f / (float)NN;
        const float mu   = red[t] * invn;
        const float var  = red[t + 256] * invn - mu * mu;
        const float sc   = gamma[t] * rsqrtf(var + EPSF);
        ss[t]       = sc;
        ss[256 + t] = beta[t] - mu * sc;
    }
}

// ---------------- agg2 (rolling) + bias + relu + dot with Wl -> u, w ----------
__global__ __launch_bounds__(256) void agg2_dots(const ushort* __restrict__ H2,
                                                 const float* __restrict__ b2,
                                                 const float* __restrict__ Wl,
                                                 float* __restrict__ u,
                                                 float* __restrict__ w)
{
    const int b = blockIdx.x, t = threadIdx.x;
    const int wave = t >> 6, lane = t & 63;
    const int v0 = b * 32;
    const float wla = Wl[t], wlb = Wl[256 + t], bias = b2[t];
    __shared__ float Up[4][32], Wp[4][32];

    float S = 0.f;
    #pragma unroll
    for (int o = -8; o <= 8; ++o)
        S += bf2f(H2[(size_t)wrapN(v0 + o) * 256 + t]);

    const float inv17 = 1.0f / 17.0f;
    for (int i = 0; i < 32; ++i) {
        const int v = v0 + i;
        const float add = bf2f(H2[(size_t)wrapN(v + 9) * 256 + t]);
        const float sub = bf2f(H2[(size_t)wrapN(v - 8) * 256 + t]);
        const float h = fmaxf(S * inv17 + bias, 0.f);
        float pu = h * wla, pw = h * wlb;
        #pragma unroll
        for (int off = 32; off > 0; off >>= 1) {
            pu += __shfl_down(pu, off);
            pw += __shfl_down(pw, off);
        }
        if (lane == 0) { Up[wave][i] = pu; Wp[wave][i] = pw; }
        S += add - sub;
    }
    __syncthreads();
    if (t < 32) {
        u[v0 + t] = Up[0][t] + Up[1][t] + Up[2][t] + Up[3][t];
        w[v0 + t] = Wp[0][t] + Wp[1][t] + Wp[2][t] + Wp[3][t];
    }
}

// ---------------- fused P + edge outputs ----------------
// 625 blocks x 512 threads; block b covers nodes [v0, v0+32) on both edge halves.
__global__ __launch_bounds__(512) void out_fused(const float* __restrict__ u,
                                                 const float* __restrict__ w,
                                                 const float* __restrict__ blp,
                                                 float* __restrict__ out)
{
    const int b = blockIdx.x, t = threadIdx.x;
    const int v0 = b * 32;
    __shared__ float uS[56];   // u[v0-8 .. v0+47]
    __shared__ float wS[40];   // w[v0 .. v0+39]
    __shared__ float PS[40];   // P[v0 .. v0+39]

    if (t < 56) uS[t] = u[wrapN(v0 - 8 + t)];
    else if (t < 96) wS[t - 56] = w[wrapN(v0 + (t - 56))];
    __syncthreads();
    if (t < 40) {
        float s = uS[t + 8] + 16.0f * wS[t];
        #pragma unroll
        for (int o = 1; o <= 8; ++o)
            s += uS[t + 8 + o] + uS[t + 8 - o];
        PS[t] = s;
    }
    __syncthreads();

    const float blv = blp[0];
    const float inv17 = 1.0f / 17.0f;
    if (t < 256) {
        const int c  = v0 * 8 + t;
        const int vi = t >> 3;                       // v - v0, 0..31
        const int ti = vi + 1 + (c & 7);             // tt - v0, 1..39
        out[c] = sigmoidf_((PS[vi] + wS[ti]) * inv17 + blv);
    } else {
        const int e  = v0 * 8 + (t - 256);
        const int ti = (t - 256) >> 3;               // tt - v0
        const int vi = ti + 1 + (e & 7);             // v - v0, 1..39
        out[NK + e] = sigmoidf_((PS[vi] + wS[ti]) * inv17 + blv);
    }
}

// ---------------- launch ----------------
extern "C" void kernel_launch(void* const* d_in, const int* in_sizes, int n_in,
                              void* d_out, int out_size, void* d_ws, size_t ws_size,
                              hipStream_t stream)
{
    const float* x      = (const float*)d_in[0];
    const float* W1     = (const float*)d_in[1];
    const float* b1     = (const float*)d_in[2];
    const float* gamma1 = (const float*)d_in[3];
    const float* beta1  = (const float*)d_in[4];
    const float* W2     = (const float*)d_in[5];
    const float* b2     = (const float*)d_in[6];
    const float* Wl     = (const float*)d_in[7];
    const float* bl     = (const float*)d_in[8];
    float* out = (float*)d_out;

    float* part  = (float*)d_ws;                     // [625,512]
    float* part2 = part + 625 * 512;                 // [25,512]
    float* ss    = part2 + 25 * 512;                 // [512]
    float* u     = ss + 512;                         // [NN]
    float* wv    = u + NN;                           // [NN]
    ushort* A    = (ushort*)(wv + NN);               // [NN,256] bf16
    ushort* H    = A + (size_t)NN * 256;             // [NN,256] bf16 (H1/H2)
    ushort* W1t  = H + (size_t)NN * 256;             // [256,128]
    ushort* W2t  = W1t + 256 * 128;                  // [256,256]

    // 1) weight transposes
    prep_w<<<96, 256, 0, stream>>>(W1, W2, W1t, W2t);
    // 2) H1 = cast(x) @ W1
    gemm1_kernel<<<dim3(313, 2), 512, 0, stream>>>(x, W1t, H);
    // 3) agg1 + b1 -> A (bf16), fused BN partials
    agg1_bn<<<625, 256, 0, stream>>>(H, b1, A, part);
    // 4) BN reduce + finalize
    bn_reduce<<<25, 512, 0, stream>>>(part, part2);
    bn_finalize<<<1, 512, 0, stream>>>(part2, gamma1, beta1, ss);
    // 5) H2 = relu(bn(A)) @ W2  (BN fused in staging)
    gemm2_kernel<<<dim3(313, 2), 512, 0, stream>>>(A, ss, W2t, H);
    // 6) agg2 + b2 + relu + dots -> u, w
    agg2_dots<<<625, 256, 0, stream>>>(H, b2, Wl, u, wv);
    // 7) P + edge outputs (fused)
    out_fused<<<625, 512, 0, stream>>>(u, wv, bl, out);
}

// Round 6
// 64.692 us; speedup vs baseline: 1.1768x; 1.0438x over previous
//
#include <hip/hip_runtime.h>
#include <hip/hip_bf16.h>
#include <math.h>

#define NN    20000
#define NK    160000          // NN*8
#define NEDGE 320000
#define HID   256
#define INFEAT 128
#define EPSF  1e-5f

typedef __bf16  bf16x8 __attribute__((ext_vector_type(8)));
typedef float   f32x4  __attribute__((ext_vector_type(4)));
typedef ushort  u16x8  __attribute__((ext_vector_type(8)));

__device__ __forceinline__ float sigmoidf_(float x) { return 1.0f / (1.0f + expf(-x)); }

__device__ __forceinline__ ushort f2bf(float f) {
    __hip_bfloat16 h = __float2bfloat16(f);
    return __builtin_bit_cast(ushort, h);
}
__device__ __forceinline__ float bf2f(ushort u) {
    return __builtin_bit_cast(float, ((unsigned int)u) << 16);
}
__device__ __forceinline__ int wrapN(int v) {
    return (v < 0) ? v + NN : ((v >= NN) ? v - NN : v);
}

#define LDSP(p) ((__attribute__((address_space(3))) unsigned int*)(p))
#define GBLP(p) ((const __attribute__((address_space(1))) unsigned int*)(p))
#define GLD16(g, l) __builtin_amdgcn_global_load_lds(GBLP(g), LDSP(l), 16, 0, 0)

// ---------------- prep: W1^T, W2^T in bf16; init bn counter ----------------
__global__ __launch_bounds__(256) void prep_w(const float* __restrict__ W1,
                                              const float* __restrict__ W2,
                                              ushort* __restrict__ W1t,
                                              ushort* __restrict__ W2t,
                                              unsigned* __restrict__ cnt)
{
    const int b = blockIdx.x, t = threadIdx.x;
    if (b == 0 && t == 0) *cnt = 0u;
    if (b < 32) {
        const int e = b * 1024 + t * 4;
        ushort4 o;
        #pragma unroll
        for (int j = 0; j < 4; ++j) {
            const int ee = e + j;
            const int n = ee >> 7, k = ee & 127;   // W1t[n][k] = W1[k][n]
            ((ushort*)&o)[j] = f2bf(W1[k * 256 + n]);
        }
        *reinterpret_cast<ushort4*>(W1t + e) = o;
    } else {
        const int e = (b - 32) * 1024 + t * 4;
        ushort4 o;
        #pragma unroll
        for (int j = 0; j < 4; ++j) {
            const int ee = e + j;
            const int n = ee >> 8, k = ee & 255;   // W2t[n][k] = W2[k][n]
            ((ushort*)&o)[j] = f2bf(W2[k * 256 + n]);
        }
        *reinterpret_cast<ushort4*>(W2t + e) = o;
    }
}

// ======== GEMM geometry: 64(M) x 128(N) tile, BK=64, 512 threads = 8 waves ========
// LDS rows 128B, XOR swizzle on 16B chunks: phys = log ^ (row&7).

// ---------------- GEMM1: H1 = cast_bf16(x) @ W1 (W1t[256][128]) ----------------
__global__ __launch_bounds__(512) void gemm1_kernel(const float* __restrict__ X,
                                                    const ushort* __restrict__ Bt,
                                                    ushort* __restrict__ C)
{
    __shared__ alignas(16) char As[8192];
    __shared__ alignas(16) char Bs[16384];

    const int bm = blockIdx.x * 64;
    const int bn = blockIdx.y * 128;
    const int t = threadIdx.x;
    const int wave = t >> 6, lane = t & 63;
    const int wr = (wave >> 2) * 32;
    const int wc = (wave & 3) * 32;

    f32x4 acc[2][2] = {};

    for (int kt = 0; kt < 2; ++kt) {
        const int k0 = kt * 64;
        {
            const int row = t >> 3;
            const int lk  = t & 7;
            const int pc  = lk ^ (row & 7);
            int rg = bm + row; if (rg >= NN) rg = NN - 1;
            const float4 v0 = *reinterpret_cast<const float4*>(X + (size_t)rg * INFEAT + k0 + lk * 8);
            const float4 v1 = *reinterpret_cast<const float4*>(X + (size_t)rg * INFEAT + k0 + lk * 8 + 4);
            u16x8 p;
            p[0] = f2bf(v0.x); p[1] = f2bf(v0.y); p[2] = f2bf(v0.z); p[3] = f2bf(v0.w);
            p[4] = f2bf(v1.x); p[5] = f2bf(v1.y); p[6] = f2bf(v1.z); p[7] = f2bf(v1.w);
            *reinterpret_cast<u16x8*>(As + row * 128 + pc * 16) = p;
        }
        #pragma unroll
        for (int it = 0; it < 2; ++it) {
            const int cb  = (it * 8 + wave) * 64 + lane;
            const int row = cb >> 3;
            const int lk  = (cb & 7) ^ (row & 7);
            GLD16(Bt + (size_t)(bn + row) * INFEAT + k0 + lk * 8, Bs + (it * 8 + wave) * 1024);
        }
        __syncthreads();

        #pragma unroll
        for (int kk = 0; kk < 2; ++kk) {
            const int klog = kk * 64 + ((lane >> 4) << 4);
            bf16x8 af[2], bfv[2];
            #pragma unroll
            for (int mi = 0; mi < 2; ++mi) {
                const int row = wr + mi * 16 + (lane & 15);
                af[mi] = *reinterpret_cast<const bf16x8*>(As + row * 128 + (klog ^ ((row & 7) << 4)));
            }
            #pragma unroll
            for (int ni = 0; ni < 2; ++ni) {
                const int row = wc + ni * 16 + (lane & 15);
                bfv[ni] = *reinterpret_cast<const bf16x8*>(Bs + row * 128 + (klog ^ ((row & 7) << 4)));
            }
            #pragma unroll
            for (int mi = 0; mi < 2; ++mi)
                #pragma unroll
                for (int ni = 0; ni < 2; ++ni)
                    acc[mi][ni] = __builtin_amdgcn_mfma_f32_16x16x32_bf16(af[mi], bfv[ni], acc[mi][ni], 0, 0, 0);
        }
        __syncthreads();
    }

    #pragma unroll
    for (int mi = 0; mi < 2; ++mi)
        #pragma unroll
        for (int ni = 0; ni < 2; ++ni)
            #pragma unroll
            for (int r = 0; r < 4; ++r) {
                const int row = bm + wr + mi * 16 + ((lane >> 4) << 2) + r;
                if (row < NN)
                    C[(size_t)row * 256 + bn + wc + ni * 16 + (lane & 15)] = f2bf(acc[mi][ni][r]);
            }
}

// ---------------- GEMM2: H2 = relu(bn(A)) @ W2 (W2t[256][256]) ----------------
__global__ __launch_bounds__(512) void gemm2_kernel(const ushort* __restrict__ Ab,
                                                    const float* __restrict__ ss,
                                                    const ushort* __restrict__ Bt,
                                                    ushort* __restrict__ C)
{
    __shared__ alignas(16) char As[8192];
    __shared__ alignas(16) char Bs[16384];

    const int bm = blockIdx.x * 64;
    const int bn = blockIdx.y * 128;
    const int t = threadIdx.x;
    const int wave = t >> 6, lane = t & 63;
    const int wr = (wave >> 2) * 32;
    const int wc = (wave & 3) * 32;

    f32x4 acc[2][2] = {};

    for (int kt = 0; kt < 4; ++kt) {
        const int k0 = kt * 64;
        {
            const int row = t >> 3;
            const int lk  = t & 7;
            const int pc  = lk ^ (row & 7);
            int rg = bm + row; if (rg >= NN) rg = NN - 1;
            const int f0 = k0 + lk * 8;
            const u16x8 a = *reinterpret_cast<const u16x8*>(Ab + (size_t)rg * 256 + f0);
            const float4 sc0 = *reinterpret_cast<const float4*>(ss + f0);
            const float4 sc1 = *reinterpret_cast<const float4*>(ss + f0 + 4);
            const float4 sh0 = *reinterpret_cast<const float4*>(ss + 256 + f0);
            const float4 sh1 = *reinterpret_cast<const float4*>(ss + 256 + f0 + 4);
            u16x8 p;
            p[0] = f2bf(fmaxf(bf2f(a[0]) * sc0.x + sh0.x, 0.f));
            p[1] = f2bf(fmaxf(bf2f(a[1]) * sc0.y + sh0.y, 0.f));
            p[2] = f2bf(fmaxf(bf2f(a[2]) * sc0.z + sh0.z, 0.f));
            p[3] = f2bf(fmaxf(bf2f(a[3]) * sc0.w + sh0.w, 0.f));
            p[4] = f2bf(fmaxf(bf2f(a[4]) * sc1.x + sh1.x, 0.f));
            p[5] = f2bf(fmaxf(bf2f(a[5]) * sc1.y + sh1.y, 0.f));
            p[6] = f2bf(fmaxf(bf2f(a[6]) * sc1.z + sh1.z, 0.f));
            p[7] = f2bf(fmaxf(bf2f(a[7]) * sc1.w + sh1.w, 0.f));
            *reinterpret_cast<u16x8*>(As + row * 128 + pc * 16) = p;
        }
        #pragma unroll
        for (int it = 0; it < 2; ++it) {
            const int cb  = (it * 8 + wave) * 64 + lane;
            const int row = cb >> 3;
            const int lk  = (cb & 7) ^ (row & 7);
            GLD16(Bt + (size_t)(bn + row) * 256 + k0 + lk * 8, Bs + (it * 8 + wave) * 1024);
        }
        __syncthreads();

        #pragma unroll
        for (int kk = 0; kk < 2; ++kk) {
            const int klog = kk * 64 + ((lane >> 4) << 4);
            bf16x8 af[2], bfv[2];
            #pragma unroll
            for (int mi = 0; mi < 2; ++mi) {
                const int row = wr + mi * 16 + (lane & 15);
                af[mi] = *reinterpret_cast<const bf16x8*>(As + row * 128 + (klog ^ ((row & 7) << 4)));
            }
            #pragma unroll
            for (int ni = 0; ni < 2; ++ni) {
                const int row = wc + ni * 16 + (lane & 15);
                bfv[ni] = *reinterpret_cast<const bf16x8*>(Bs + row * 128 + (klog ^ ((row & 7) << 4)));
            }
            #pragma unroll
            for (int mi = 0; mi < 2; ++mi)
                #pragma unroll
                for (int ni = 0; ni < 2; ++ni)
                    acc[mi][ni] = __builtin_amdgcn_mfma_f32_16x16x32_bf16(af[mi], bfv[ni], acc[mi][ni], 0, 0, 0);
        }
        __syncthreads();
    }

    #pragma unroll
    for (int mi = 0; mi < 2; ++mi)
        #pragma unroll
        for (int ni = 0; ni < 2; ++ni)
            #pragma unroll
            for (int r = 0; r < 4; ++r) {
                const int row = bm + wr + mi * 16 + ((lane >> 4) << 2) + r;
                if (row < NN)
                    C[(size_t)row * 256 + bn + wc + ni * 16 + (lane & 15)] = f2bf(acc[mi][ni][r]);
            }
}

// ---------------- agg1 + bias (vectorized rolling) + BN partials ----------------
// 313 blocks x 256 threads. Thread: fg = t&31 (8 feats), nl = t>>5 (8 nodes strip).
__global__ __launch_bounds__(256) void agg1_bn(const ushort* __restrict__ H1,
                                               const float* __restrict__ b1,
                                               ushort* __restrict__ A,
                                               float* __restrict__ part)
{
    const int b = blockIdx.x, t = threadIdx.x;
    const int fg = t & 31, nl = t >> 5;
    const int f0 = fg * 8;
    const int vstart = b * 64 + nl * 8;
    __shared__ float red[8][512];

    float bias[8];
    #pragma unroll
    for (int j = 0; j < 8; ++j) bias[j] = b1[f0 + j];

    float S[8] = {};
    #pragma unroll
    for (int o = -8; o <= 8; ++o) {
        const u16x8 h = *reinterpret_cast<const u16x8*>(H1 + (size_t)wrapN(vstart + o) * 256 + f0);
        #pragma unroll
        for (int j = 0; j < 8; ++j) S[j] += bf2f(h[j]);
    }
    float s[8] = {}, s2[8] = {};
    const float inv17 = 1.0f / 17.0f;
    for (int i = 0; i < 8; ++i) {
        const int v = vstart + i;
        const u16x8 hadd = *reinterpret_cast<const u16x8*>(H1 + (size_t)wrapN(v + 9) * 256 + f0);
        const u16x8 hsub = *reinterpret_cast<const u16x8*>(H1 + (size_t)wrapN(v - 8) * 256 + f0);
        if (v < NN) {
            u16x8 o;
            #pragma unroll
            for (int j = 0; j < 8; ++j) {
                const float val = S[j] * inv17 + bias[j];
                o[j] = f2bf(val);
                s[j] += val; s2[j] += val * val;
            }
            *reinterpret_cast<u16x8*>(A + (size_t)v * 256 + f0) = o;
        }
        #pragma unroll
        for (int j = 0; j < 8; ++j) S[j] += bf2f(hadd[j]) - bf2f(hsub[j]);
    }
    #pragma unroll
    for (int j = 0; j < 8; ++j) {
        red[nl][f0 + j]       = s[j];
        red[nl][256 + f0 + j] = s2[j];
    }
    __syncthreads();
    #pragma unroll
    for (int h = 0; h < 2; ++h) {
        const int f = t + h * 256;
        float tot = 0.f;
        #pragma unroll
        for (int q = 0; q < 8; ++q) tot += red[q][f];
        part[(size_t)b * 512 + f] = tot;
    }
}

// ---------------- BN reduce + finalize in ONE kernel (last-block pattern) ------
__global__ __launch_bounds__(512) void bn_comb(const float* __restrict__ part,
                                               float* __restrict__ part2,
                                               const float* __restrict__ gamma,
                                               const float* __restrict__ beta,
                                               float* __restrict__ ss,
                                               unsigned* __restrict__ cnt)
{
    const int b = blockIdx.x, t = threadIdx.x;   // 32 blocks x 512 threads
    float s = 0.f;
    const int r0 = b * 10;
    const int r1 = (r0 + 10 < 313) ? r0 + 10 : 313;
    for (int r = r0; r < r1; ++r)
        s += part[(size_t)r * 512 + t];
    part2[(size_t)b * 512 + t] = s;
    __threadfence();
    __syncthreads();
    __shared__ unsigned lastf;
    if (t == 0) lastf = (atomicAdd(cnt, 1u) == 31u) ? 1u : 0u;
    __syncthreads();
    if (!lastf) return;
    if (t == 0) *cnt = 0u;
    __threadfence();
    float tot = 0.f;
    #pragma unroll
    for (int j = 0; j < 32; ++j)
        tot += part2[(size_t)j * 512 + t];
    __shared__ float red[512];
    red[t] = tot;
    __syncthreads();
    if (t < 256) {
        const float invn = 1.0f / (float)NN;
        const float mu   = red[t] * invn;
        const float var  = red[t + 256] * invn - mu * mu;
        const float sc   = gamma[t] * rsqrtf(var + EPSF);
        ss[t]       = sc;
        ss[256 + t] = beta[t] - mu * sc;
    }
}

// ---------------- agg2 + relu + dots + P + edge outputs, fully fused ----------
// 313 blocks x 256 threads; block covers output nodes [v0, v0+64), halo u/w for 88.
__global__ __launch_bounds__(256) void agg2_out(const ushort* __restrict__ H2,
                                                const float* __restrict__ b2,
                                                const float* __restrict__ Wl,
                                                const float* __restrict__ blp,
                                                float* __restrict__ out)
{
    const int b = blockIdx.x, t = threadIdx.x;
    const int fg = t & 31, nl = t >> 5;
    const int f0 = fg * 8;
    const int v0 = b * 64;
    const int vstart = v0 - 8 + nl * 11;
    __shared__ float uS[88], wS[88], PS[72];

    float wla[8], wlb[8], bias[8];
    #pragma unroll
    for (int j = 0; j < 8; ++j) {
        wla[j]  = Wl[f0 + j];
        wlb[j]  = Wl[256 + f0 + j];
        bias[j] = b2[f0 + j];
    }

    float S[8] = {};
    #pragma unroll
    for (int o = -8; o <= 8; ++o) {
        const u16x8 h = *reinterpret_cast<const u16x8*>(H2 + (size_t)wrapN(vstart + o) * 256 + f0);
        #pragma unroll
        for (int j = 0; j < 8; ++j) S[j] += bf2f(h[j]);
    }
    const float inv17 = 1.0f / 17.0f;
    for (int i = 0; i < 11; ++i) {
        const int v = vstart + i;
        const u16x8 hadd = *reinterpret_cast<const u16x8*>(H2 + (size_t)wrapN(v + 9) * 256 + f0);
        const u16x8 hsub = *reinterpret_cast<const u16x8*>(H2 + (size_t)wrapN(v - 8) * 256 + f0);
        float pu = 0.f, pw = 0.f;
        #pragma unroll
        for (int j = 0; j < 8; ++j) {
            const float h = fmaxf(S[j] * inv17 + bias[j], 0.f);
            pu += h * wla[j];
            pw += h * wlb[j];
        }
        #pragma unroll
        for (int off = 16; off > 0; off >>= 1) {
            pu += __shfl_down(pu, off);
            pw += __shfl_down(pw, off);
        }
        if (fg == 0) { uS[nl * 11 + i] = pu; wS[nl * 11 + i] = pw; }
        #pragma unroll
        for (int j = 0; j < 8; ++j) S[j] += bf2f(hadd[j]) - bf2f(hsub[j]);
    }
    __syncthreads();
    if (t < 72) {
        float s = uS[t + 8] + 16.0f * wS[t + 8];
        #pragma unroll
        for (int o = 1; o <= 8; ++o)
            s += uS[t + 8 + o] + uS[t + 8 - o];
        PS[t] = s;
    }
    __syncthreads();

    const float blv = blp[0];
    #pragma unroll
    for (int r = 0; r < 4; ++r) {
        const int q  = t + r * 256;          // [0,1024)
        const int qq = q & 511;
        const int p  = qq >> 3, off = qq & 7;
        const int v  = v0 + p;
        if (v >= NN) continue;
        float val;
        int c;
        if (q < 512) {                        // forward edge (v -> v+1+off)
            val = (PS[p] + wS[p + 9 + off]) * inv17 + blv;
            c = v * 8 + off;
        } else {                              // reverse edge (tt = v)
            val = (PS[p + 1 + off] + wS[p + 8]) * inv17 + blv;
            c = NK + v * 8 + off;
        }
        out[c] = sigmoidf_(val);
    }
}

// ---------------- launch ----------------
extern "C" void kernel_launch(void* const* d_in, const int* in_sizes, int n_in,
                              void* d_out, int out_size, void* d_ws, size_t ws_size,
                              hipStream_t stream)
{
    const float* x      = (const float*)d_in[0];
    const float* W1     = (const float*)d_in[1];
    const float* b1     = (const float*)d_in[2];
    const float* gamma1 = (const float*)d_in[3];
    const float* beta1  = (const float*)d_in[4];
    const float* W2     = (const float*)d_in[5];
    const float* b2     = (const float*)d_in[6];
    const float* Wl     = (const float*)d_in[7];
    const float* bl     = (const float*)d_in[8];
    float* out = (float*)d_out;

    float*    part  = (float*)d_ws;                  // [313,512]
    float*    part2 = part + 313 * 512;              // [32,512]
    float*    ss    = part2 + 32 * 512;              // [512]
    unsigned* cnt   = (unsigned*)(ss + 512);         // [4] (1 used, pad to 16B)
    ushort*   A     = (ushort*)(ss + 512 + 4);       // [NN,256] bf16
    ushort*   H     = A + (size_t)NN * 256;          // [NN,256] bf16 (H1/H2)
    ushort*   W1t   = H + (size_t)NN * 256;          // [256,128]
    ushort*   W2t   = W1t + 256 * 128;               // [256,256]

    // 1) weight transposes + counter init
    prep_w<<<96, 256, 0, stream>>>(W1, W2, W1t, W2t, cnt);
    // 2) H1 = cast(x) @ W1
    gemm1_kernel<<<dim3(313, 2), 512, 0, stream>>>(x, W1t, H);
    // 3) agg1 + b1 -> A (bf16), BN partials
    agg1_bn<<<313, 256, 0, stream>>>(H, b1, A, part);
    // 4) BN reduce + finalize (one kernel, last-block pattern)
    bn_comb<<<32, 512, 0, stream>>>(part, part2, gamma1, beta1, ss, cnt);
    // 5) H2 = relu(bn(A)) @ W2  (BN fused in staging)
    gemm2_kernel<<<dim3(313, 2), 512, 0, stream>>>(A, ss, W2t, H);
    // 6) agg2 + dots + P + edge outputs (fully fused)
    agg2_out<<<313, 256, 0, stream>>>(H, b2, Wl, bl, out);
}

// Round 7
// 63.059 us; speedup vs baseline: 1.2073x; 1.0259x over previous
//
#include <hip/hip_runtime.h>
#include <hip/hip_bf16.h>
#include <math.h>

#define NN    20000
#define NK    160000          // NN*8
#define NEDGE 320000
#define HID   256
#define INFEAT 128
#define EPSF  1e-5f

typedef __bf16  bf16x8 __attribute__((ext_vector_type(8)));
typedef float   f32x4  __attribute__((ext_vector_type(4)));
typedef ushort  u16x8  __attribute__((ext_vector_type(8)));

__device__ __forceinline__ float sigmoidf_(float x) { return 1.0f / (1.0f + expf(-x)); }

__device__ __forceinline__ ushort f2bf(float f) {
    __hip_bfloat16 h = __float2bfloat16(f);
    return __builtin_bit_cast(ushort, h);
}
__device__ __forceinline__ float bf2f(ushort u) {
    return __builtin_bit_cast(float, ((unsigned int)u) << 16);
}
__device__ __forceinline__ int wrapN(int v) {
    return (v < 0) ? v + NN : ((v >= NN) ? v - NN : v);
}

#define LDSP(p) ((__attribute__((address_space(3))) unsigned int*)(p))
#define GBLP(p) ((const __attribute__((address_space(1))) unsigned int*)(p))
#define GLD16(g, l) __builtin_amdgcn_global_load_lds(GBLP(g), LDSP(l), 16, 0, 0)

// ---------------- prep: W transposes, zero u/w, cnt, and xab = agg(x) ----------
// blocks: [0,32) W1t, [32,96) W2t, [96,136) zero u/w, [136,215) aggx.
__global__ __launch_bounds__(256) void prep_kernel(const float* __restrict__ x,
                                                   const float* __restrict__ W1,
                                                   const float* __restrict__ W2,
                                                   ushort* __restrict__ W1t,
                                                   ushort* __restrict__ W2t,
                                                   ushort* __restrict__ xab,
                                                   float* __restrict__ uzero,
                                                   unsigned* __restrict__ cnt)
{
    const int b = blockIdx.x, t = threadIdx.x;
    if (b == 0 && t == 0) *cnt = 0u;
    if (b < 32) {
        const int e = b * 1024 + t * 4;
        ushort4 o;
        #pragma unroll
        for (int j = 0; j < 4; ++j) {
            const int ee = e + j;
            const int n = ee >> 7, k = ee & 127;   // W1t[n][k] = W1[k][n]
            ((ushort*)&o)[j] = f2bf(W1[k * 256 + n]);
        }
        *reinterpret_cast<ushort4*>(W1t + e) = o;
    } else if (b < 96) {
        const int e = (b - 32) * 1024 + t * 4;
        ushort4 o;
        #pragma unroll
        for (int j = 0; j < 4; ++j) {
            const int ee = e + j;
            const int n = ee >> 8, k = ee & 255;   // W2t[n][k] = W2[k][n]
            ((ushort*)&o)[j] = f2bf(W2[k * 256 + n]);
        }
        *reinterpret_cast<ushort4*>(W2t + e) = o;
    } else if (b < 136) {
        const int idx = (b - 96) * 1024 + t * 4;
        if (idx < 2 * NN)
            *reinterpret_cast<float4*>(uzero + idx) = make_float4(0.f, 0.f, 0.f, 0.f);
    } else {
        // aggx: xab[v] = (1/17) * sum_{o=-8..8} x[v+o], bf16 out.
        const int bb = b - 136;
        const int fg = t & 15, nl = t >> 4;
        const int f0 = fg * 8;
        const int vstart = bb * 256 + nl * 16;
        float S[8] = {};
        #pragma unroll
        for (int o = -8; o <= 8; ++o) {
            const float* r = x + (size_t)wrapN(vstart + o) * INFEAT + f0;
            const float4 a = *reinterpret_cast<const float4*>(r);
            const float4 c = *reinterpret_cast<const float4*>(r + 4);
            S[0] += a.x; S[1] += a.y; S[2] += a.z; S[3] += a.w;
            S[4] += c.x; S[5] += c.y; S[6] += c.z; S[7] += c.w;
        }
        const float inv17 = 1.0f / 17.0f;
        for (int i = 0; i < 16; ++i) {
            const int v = vstart + i;
            const float* ra = x + (size_t)wrapN(v + 9) * INFEAT + f0;
            const float* rs = x + (size_t)wrapN(v - 8) * INFEAT + f0;
            const float4 a0 = *reinterpret_cast<const float4*>(ra);
            const float4 a1 = *reinterpret_cast<const float4*>(ra + 4);
            const float4 s0 = *reinterpret_cast<const float4*>(rs);
            const float4 s1 = *reinterpret_cast<const float4*>(rs + 4);
            if (v < NN) {
                u16x8 o;
                #pragma unroll
                for (int j = 0; j < 8; ++j) o[j] = f2bf(S[j] * inv17);
                *reinterpret_cast<u16x8*>(xab + (size_t)v * INFEAT + f0) = o;
            }
            S[0] += a0.x - s0.x; S[1] += a0.y - s0.y; S[2] += a0.z - s0.z; S[3] += a0.w - s0.w;
            S[4] += a1.x - s1.x; S[5] += a1.y - s1.y; S[6] += a1.z - s1.z; S[7] += a1.w - s1.w;
        }
    }
}

// ======== GEMM geometry: 64(M) x 128(N) tile, BK=64, 512 threads = 8 waves ========
// LDS rows 128B, XOR swizzle on 16B chunks: phys = log ^ (row&7).

// ---------------- GEMM1: A = xab @ W1 + b1; epilogue emits BN partials ----------
__global__ __launch_bounds__(512) void gemm1_kernel(const ushort* __restrict__ Ab,
                                                    const ushort* __restrict__ Bt,
                                                    const float* __restrict__ b1,
                                                    ushort* __restrict__ C,
                                                    float* __restrict__ part)
{
    __shared__ alignas(16) char As[8192];
    __shared__ alignas(16) char Bs[16384];
    __shared__ float sS[8][32], s2S[8][32];

    const int bm = blockIdx.x * 64;
    const int bn = blockIdx.y * 128;
    const int t = threadIdx.x;
    const int wave = t >> 6, lane = t & 63;
    const int wr = (wave >> 2) * 32;
    const int wc = (wave & 3) * 32;

    f32x4 acc[2][2] = {};

    #pragma unroll
    for (int kt = 0; kt < 2; ++kt) {
        const int k0 = kt * 64;
        {   // stage A (64x64 bf16) via GLD16
            const int c   = wave * 64 + lane;
            const int row = c >> 3;
            const int lk  = (c & 7) ^ (row & 7);
            int rg = bm + row; if (rg >= NN) rg = NN - 1;
            GLD16(Ab + (size_t)rg * INFEAT + k0 + lk * 8, As + wave * 1024);
        }
        #pragma unroll
        for (int it = 0; it < 2; ++it) {   // stage B (128x64)
            const int cb  = (it * 8 + wave) * 64 + lane;
            const int row = cb >> 3;
            const int lk  = (cb & 7) ^ (row & 7);
            GLD16(Bt + (size_t)(bn + row) * INFEAT + k0 + lk * 8, Bs + (it * 8 + wave) * 1024);
        }
        __syncthreads();

        #pragma unroll
        for (int kk = 0; kk < 2; ++kk) {
            const int klog = kk * 64 + ((lane >> 4) << 4);
            bf16x8 af[2], bfv[2];
            #pragma unroll
            for (int mi = 0; mi < 2; ++mi) {
                const int row = wr + mi * 16 + (lane & 15);
                af[mi] = *reinterpret_cast<const bf16x8*>(As + row * 128 + (klog ^ ((row & 7) << 4)));
            }
            #pragma unroll
            for (int ni = 0; ni < 2; ++ni) {
                const int row = wc + ni * 16 + (lane & 15);
                bfv[ni] = *reinterpret_cast<const bf16x8*>(Bs + row * 128 + (klog ^ ((row & 7) << 4)));
            }
            #pragma unroll
            for (int mi = 0; mi < 2; ++mi)
                #pragma unroll
                for (int ni = 0; ni < 2; ++ni)
                    acc[mi][ni] = __builtin_amdgcn_mfma_f32_16x16x32_bf16(af[mi], bfv[ni], acc[mi][ni], 0, 0, 0);
        }
        __syncthreads();
    }

    // epilogue: bias, store A (bf16), BN partials (deterministic shuffle reduce)
    #pragma unroll
    for (int ni = 0; ni < 2; ++ni) {
        const int colL = wc + ni * 16 + (lane & 15);
        const float bv = b1[bn + colL];
        float sv = 0.f, s2v = 0.f;
        #pragma unroll
        for (int mi = 0; mi < 2; ++mi)
            #pragma unroll
            for (int r = 0; r < 4; ++r) {
                const int row = bm + wr + mi * 16 + ((lane >> 4) << 2) + r;
                if (row < NN) {
                    const float val = acc[mi][ni][r] + bv;
                    C[(size_t)row * 256 + bn + colL] = f2bf(val);
                    sv += val; s2v += val * val;
                }
            }
        sv  += __shfl_xor(sv, 16);  sv  += __shfl_xor(sv, 32);
        s2v += __shfl_xor(s2v, 16); s2v += __shfl_xor(s2v, 32);
        if (lane < 16) { sS[wave][ni * 16 + lane] = sv; s2S[wave][ni * 16 + lane] = s2v; }
    }
    __syncthreads();
    if (t < 128) {
        const int wcx = t >> 5, wi = t & 31;
        const float stot  = sS[wcx][wi]  + sS[wcx + 4][wi];
        const float s2tot = s2S[wcx][wi] + s2S[wcx + 4][wi];
        part[(size_t)blockIdx.x * 512 + blockIdx.y * 128 + t]       = stot;
        part[(size_t)blockIdx.x * 512 + 256 + blockIdx.y * 128 + t] = s2tot;
    }
}

// ---------------- BN reduce + finalize (last-block pattern) --------------------
__global__ __launch_bounds__(512) void bn_comb(const float* __restrict__ part,
                                               float* __restrict__ part2,
                                               const float* __restrict__ gamma,
                                               const float* __restrict__ beta,
                                               float* __restrict__ ss,
                                               unsigned* __restrict__ cnt)
{
    const int b = blockIdx.x, t = threadIdx.x;   // 32 blocks x 512
    float s = 0.f;
    const int r0 = b * 10;
    const int r1 = (r0 + 10 < 313) ? r0 + 10 : 313;
    for (int r = r0; r < r1; ++r)
        s += part[(size_t)r * 512 + t];
    part2[(size_t)b * 512 + t] = s;
    __threadfence();
    __syncthreads();
    __shared__ unsigned lastf;
    if (t == 0) lastf = (atomicAdd(cnt, 1u) == 31u) ? 1u : 0u;
    __syncthreads();
    if (!lastf) return;
    if (t == 0) *cnt = 0u;
    __threadfence();
    float tot = 0.f;
    #pragma unroll
    for (int j = 0; j < 32; ++j)
        tot += part2[(size_t)j * 512 + t];
    __shared__ float red[512];
    red[t] = tot;
    __syncthreads();
    if (t < 256) {
        const float invn = 1.0f / (float)NN;
        const float mu   = red[t] * invn;
        const float var  = red[t + 256] * invn - mu * mu;
        const float sc   = gamma[t] * rsqrtf(var + EPSF);
        ss[t]       = sc;
        ss[256 + t] = beta[t] - mu * sc;
    }
}

// ---------------- mid: g = agg2(relu(bn(A))), bf16 ----------------------------
// 313 blocks x 256 threads; fg = t&31 (8 feats), nl = t>>5 (8 strips of 8 nodes).
__global__ __launch_bounds__(256) void mid_kernel(const ushort* __restrict__ A,
                                                  const float* __restrict__ ss,
                                                  ushort* __restrict__ g)
{
    const int b = blockIdx.x, t = threadIdx.x;
    const int fg = t & 31, nl = t >> 5;
    const int f0 = fg * 8;
    const int vstart = b * 64 + nl * 8;

    float sc[8], sh[8];
    #pragma unroll
    for (int j = 0; j < 8; ++j) { sc[j] = ss[f0 + j]; sh[j] = ss[256 + f0 + j]; }

    float S[8] = {};
    #pragma unroll
    for (int o = -8; o <= 8; ++o) {
        const u16x8 h = *reinterpret_cast<const u16x8*>(A + (size_t)wrapN(vstart + o) * 256 + f0);
        #pragma unroll
        for (int j = 0; j < 8; ++j) S[j] += fmaxf(bf2f(h[j]) * sc[j] + sh[j], 0.f);
    }
    const float inv17 = 1.0f / 17.0f;
    for (int i = 0; i < 8; ++i) {
        const int v = vstart + i;
        const u16x8 ha = *reinterpret_cast<const u16x8*>(A + (size_t)wrapN(v + 9) * 256 + f0);
        const u16x8 hs = *reinterpret_cast<const u16x8*>(A + (size_t)wrapN(v - 8) * 256 + f0);
        if (v < NN) {
            u16x8 o;
            #pragma unroll
            for (int j = 0; j < 8; ++j) o[j] = f2bf(S[j] * inv17);
            *reinterpret_cast<u16x8*>(g + (size_t)v * 256 + f0) = o;
        }
        #pragma unroll
        for (int j = 0; j < 8; ++j)
            S[j] += fmaxf(bf2f(ha[j]) * sc[j] + sh[j], 0.f)
                  - fmaxf(bf2f(hs[j]) * sc[j] + sh[j], 0.f);
    }
}

// ---------------- GEMM2: h2 = relu(g @ W2 + b2) consumed in epilogue -> u,w ----
__global__ __launch_bounds__(512) void gemm2_kernel(const ushort* __restrict__ Ab,
                                                    const ushort* __restrict__ Bt,
                                                    const float* __restrict__ b2,
                                                    const float* __restrict__ Wl,
                                                    float* __restrict__ u,
                                                    float* __restrict__ w)
{
    __shared__ alignas(16) char As[8192];
    __shared__ alignas(16) char Bs[16384];
    __shared__ float uW[4][64], wW[4][64];

    const int bm = blockIdx.x * 64;
    const int bn = blockIdx.y * 128;
    const int t = threadIdx.x;
    const int wave = t >> 6, lane = t & 63;
    const int wr = (wave >> 2) * 32;
    const int wc = (wave & 3) * 32;

    f32x4 acc[2][2] = {};

    #pragma unroll
    for (int kt = 0; kt < 4; ++kt) {
        const int k0 = kt * 64;
        {   // stage A from g
            const int c   = wave * 64 + lane;
            const int row = c >> 3;
            const int lk  = (c & 7) ^ (row & 7);
            int rg = bm + row; if (rg >= NN) rg = NN - 1;
            GLD16(Ab + (size_t)rg * 256 + k0 + lk * 8, As + wave * 1024);
        }
        #pragma unroll
        for (int it = 0; it < 2; ++it) {
            const int cb  = (it * 8 + wave) * 64 + lane;
            const int row = cb >> 3;
            const int lk  = (cb & 7) ^ (row & 7);
            GLD16(Bt + (size_t)(bn + row) * 256 + k0 + lk * 8, Bs + (it * 8 + wave) * 1024);
        }
        __syncthreads();

        #pragma unroll
        for (int kk = 0; kk < 2; ++kk) {
            const int klog = kk * 64 + ((lane >> 4) << 4);
            bf16x8 af[2], bfv[2];
            #pragma unroll
            for (int mi = 0; mi < 2; ++mi) {
                const int row = wr + mi * 16 + (lane & 15);
                af[mi] = *reinterpret_cast<const bf16x8*>(As + row * 128 + (klog ^ ((row & 7) << 4)));
            }
            #pragma unroll
            for (int ni = 0; ni < 2; ++ni) {
                const int row = wc + ni * 16 + (lane & 15);
                bfv[ni] = *reinterpret_cast<const bf16x8*>(Bs + row * 128 + (klog ^ ((row & 7) << 4)));
            }
            #pragma unroll
            for (int mi = 0; mi < 2; ++mi)
                #pragma unroll
                for (int ni = 0; ni < 2; ++ni)
                    acc[mi][ni] = __builtin_amdgcn_mfma_f32_16x16x32_bf16(af[mi], bfv[ni], acc[mi][ni], 0, 0, 0);
        }
        __syncthreads();
    }

    // epilogue: h2 = relu(acc + b2); per-row dots with Wl -> u,w (deterministic)
    float b2v[2], wav[2], wbv[2];
    #pragma unroll
    for (int ni = 0; ni < 2; ++ni) {
        const int col = bn + wc + ni * 16 + (lane & 15);
        b2v[ni] = b2[col];
        wav[ni] = Wl[col];
        wbv[ni] = Wl[256 + col];
    }
    #pragma unroll
    for (int mi = 0; mi < 2; ++mi)
        #pragma unroll
        for (int r = 0; r < 4; ++r) {
            float pu = 0.f, pw = 0.f;
            #pragma unroll
            for (int ni = 0; ni < 2; ++ni) {
                const float h = fmaxf(acc[mi][ni][r] + b2v[ni], 0.f);
                pu += h * wav[ni];
                pw += h * wbv[ni];
            }
            pu += __shfl_xor(pu, 1); pu += __shfl_xor(pu, 2);
            pu += __shfl_xor(pu, 4); pu += __shfl_xor(pu, 8);
            pw += __shfl_xor(pw, 1); pw += __shfl_xor(pw, 2);
            pw += __shfl_xor(pw, 4); pw += __shfl_xor(pw, 8);
            if ((lane & 15) == 0) {
                const int lr = wr + mi * 16 + ((lane >> 4) << 2) + r;
                uW[wave & 3][lr] = pu;
                wW[wave & 3][lr] = pw;
            }
        }
    __syncthreads();
    if (t < 64) {
        const int row = bm + t;
        if (row < NN) {
            atomicAdd(&u[row], uW[0][t] + uW[1][t] + uW[2][t] + uW[3][t]);
            atomicAdd(&w[row], wW[0][t] + wW[1][t] + wW[2][t] + wW[3][t]);
        }
    }
}

// ---------------- fused P + edge outputs (R5-verified) ------------------------
__global__ __launch_bounds__(512) void out_fused(const float* __restrict__ u,
                                                 const float* __restrict__ w,
                                                 const float* __restrict__ blp,
                                                 float* __restrict__ out)
{
    const int b = blockIdx.x, t = threadIdx.x;
    const int v0 = b * 32;
    __shared__ float uS[56];   // u[v0-8 .. v0+47]
    __shared__ float wS[40];   // w[v0 .. v0+39]
    __shared__ float PS[40];

    if (t < 56) uS[t] = u[wrapN(v0 - 8 + t)];
    else if (t < 96) wS[t - 56] = w[wrapN(v0 + (t - 56))];
    __syncthreads();
    if (t < 40) {
        float s = uS[t + 8] + 16.0f * wS[t];
        #pragma unroll
        for (int o = 1; o <= 8; ++o)
            s += uS[t + 8 + o] + uS[t + 8 - o];
        PS[t] = s;
    }
    __syncthreads();

    const float blv = blp[0];
    const float inv17 = 1.0f / 17.0f;
    if (t < 256) {
        const int c  = v0 * 8 + t;
        const int vi = t >> 3;
        const int ti = vi + 1 + (c & 7);
        out[c] = sigmoidf_((PS[vi] + wS[ti]) * inv17 + blv);
    } else {
        const int e  = v0 * 8 + (t - 256);
        const int ti = (t - 256) >> 3;
        const int vi = ti + 1 + (e & 7);
        out[NK + e] = sigmoidf_((PS[vi] + wS[ti]) * inv17 + blv);
    }
}

// ---------------- launch ----------------
extern "C" void kernel_launch(void* const* d_in, const int* in_sizes, int n_in,
                              void* d_out, int out_size, void* d_ws, size_t ws_size,
                              hipStream_t stream)
{
    const float* x      = (const float*)d_in[0];
    const float* W1     = (const float*)d_in[1];
    const float* b1     = (const float*)d_in[2];
    const float* gamma1 = (const float*)d_in[3];
    const float* beta1  = (const float*)d_in[4];
    const float* W2     = (const float*)d_in[5];
    const float* b2     = (const float*)d_in[6];
    const float* Wl     = (const float*)d_in[7];
    const float* bl     = (const float*)d_in[8];
    float* out = (float*)d_out;

    float*    part  = (float*)d_ws;                  // [313,512]
    float*    part2 = part + 313 * 512;              // [32,512]
    float*    ss    = part2 + 32 * 512;              // [512]
    unsigned* cnt   = (unsigned*)(ss + 512);         // [4]
    float*    u     = (float*)(ss + 512 + 4);        // [NN]
    float*    w     = u + NN;                        // [NN]
    ushort*   xab   = (ushort*)(w + NN);             // [NN,128] bf16
    ushort*   A     = xab + (size_t)NN * 128;        // [NN,256] bf16
    ushort*   g     = A + (size_t)NN * 256;          // [NN,256] bf16
    ushort*   W1t   = g + (size_t)NN * 256;          // [256,128]
    ushort*   W2t   = W1t + 256 * 128;               // [256,256]

    // 1) prep: W transposes, zero u/w, counter, xab = agg(x)
    prep_kernel<<<215, 256, 0, stream>>>(x, W1, W2, W1t, W2t, xab, u, cnt);
    // 2) A = xab @ W1 + b1 (BN partials in epilogue)
    gemm1_kernel<<<dim3(313, 2), 512, 0, stream>>>(xab, W1t, b1, A, part);
    // 3) BN finalize -> ss
    bn_comb<<<32, 512, 0, stream>>>(part, part2, gamma1, beta1, ss, cnt);
    // 4) g = agg2(relu(bn(A)))
    mid_kernel<<<313, 256, 0, stream>>>(A, ss, g);
    // 5) h2 = relu(g @ W2 + b2) -> dots u,w (no H2 materialization)
    gemm2_kernel<<<dim3(313, 2), 512, 0, stream>>>(g, W2t, b2, Wl, u, w);
    // 6) P + edge outputs
    out_fused<<<625, 512, 0, stream>>>(u, w, bl, out);
}